// Round 3
// baseline (300.880 us; speedup 1.0000x reference)
//
#include <hip/hip_runtime.h>
#include <hip/hip_bf16.h>
#include <math.h>

#define Nn 4096
#define Hdim 256
#define Edim 128
#define Cdim 32
#define Vdim 64
#define Kdim 20
#define G4H 1024
#define OUTS 513

#define Rr 32            // rows per GEMM tile
#define NB 8             // XCD buckets
#define LMAX 112         // max tiles per bucket (uniform data: ~82 worst)
#define MAXG (NB * LMAX) // 896 blocks

typedef short bf16x8 __attribute__((ext_vector_type(8)));
typedef float f32x4 __attribute__((ext_vector_type(4)));

__device__ __forceinline__ float sigmoidf_(float x) { return 1.0f / (1.0f + expf(-x)); }

__device__ __forceinline__ bf16x8 cvt8(float4 f0, float4 f1) {
    bf16x8 r;
    __hip_bfloat16 h;
    h = __float2bfloat16(f0.x); r[0] = *(short*)&h;
    h = __float2bfloat16(f0.y); r[1] = *(short*)&h;
    h = __float2bfloat16(f0.z); r[2] = *(short*)&h;
    h = __float2bfloat16(f0.w); r[3] = *(short*)&h;
    h = __float2bfloat16(f1.x); r[4] = *(short*)&h;
    h = __float2bfloat16(f1.y); r[5] = *(short*)&h;
    h = __float2bfloat16(f1.z); r[6] = *(short*)&h;
    h = __float2bfloat16(f1.w); r[7] = *(short*)&h;
    return r;
}

// ---------------- single bucketing kernel: histogram + scan + scatter + XCD tile list ----------------
// tlist entry i (3 ints): [k or -1] [start | rcount<<16] [hb0]
__global__ __launch_bounds__(1024) void k_bucket(const int* __restrict__ cell_id,
                                                 int* __restrict__ perm,
                                                 int* __restrict__ tlist) {
    __shared__ int cnt[Kdim], off[Kdim], cur[Kdim];
    int t = threadIdx.x;
    if (t < Kdim) cnt[t] = 0;
    __syncthreads();
    for (int i = t; i < Nn; i += 1024) atomicAdd(&cnt[cell_id[i]], 1);
    __syncthreads();
    if (t == 0) {
        int acc = 0;
        for (int k = 0; k < Kdim; k++) { off[k] = acc; cur[k] = acc; acc += cnt[k]; }
    }
    __syncthreads();
    for (int i = t; i < Nn; i += 1024) {
        int p = atomicAdd(&cur[cell_id[i]], 1);
        perm[p] = i;
    }
    // init tile list to invalid (ws is re-poisoned each call)
    for (int i = t; i < MAXG; i += 1024) tlist[3 * i] = -1;
    __syncthreads();
    if (t == 0) {
        int nt[NB];
        #pragma unroll
        for (int b = 0; b < NB; b++) nt[b] = 0;
        for (int k = 0; k < Kdim; k++) {
            int c = cnt[k];
            int tk = (c + Rr - 1) / Rr;
            if (tk == 0) continue;
            for (int hb = 0; hb < 4; hb++) {
                // greedy: whole (k,hb) unit to least-loaded bucket -> one XCD owns this W slice
                int bb = 0;
                for (int b = 1; b < NB; b++) if (nt[b] < nt[bb]) bb = b;
                for (int s = 0; s < tk; s++) {
                    int slot = nt[bb] * NB + bb;     // interleaved: slot % 8 == bucket
                    nt[bb]++;
                    if (slot < MAXG) {
                        int rc = min(Rr, c - s * Rr);
                        tlist[3 * slot + 0] = k;
                        tlist[3 * slot + 1] = (off[k] + s * Rr) | (rc << 16);
                        tlist[3 * slot + 2] = hb * 64;
                    }
                }
            }
        }
    }
}

// ---------------- loss kernel: 4 waves/block, one row per wave ----------------
__global__ __launch_bounds__(256) void k_loss(
    const float* __restrict__ vec,
    const float* __restrict__ Wlin, const float* __restrict__ blin,
    const float* __restrict__ Wec, const float* __restrict__ bec,
    const float* __restrict__ Wrel, const float* __restrict__ brel,
    const int* __restrict__ category, const int* __restrict__ true_idx,
    const int* __restrict__ ec_idx, const int* __restrict__ rel_idx,
    float* __restrict__ out)
{
    int wv = threadIdx.x >> 6;
    int lane = threadIdx.x & 63;
    int row = blockIdx.x * 4 + wv;
    __shared__ float v[4][Hdim];

    const float* vr = vec + (size_t)row * Hdim;
    ((float4*)v[wv])[lane] = ((const float4*)vr)[lane];  // wave-private: no barrier needed

    int c = category[row];
    const float* W = Wlin + ((size_t)c * Vdim + lane) * Hdim;
    float acc = 0.0f;
    #pragma unroll 4
    for (int h = 0; h < Hdim; h += 4) {
        float4 w = *(const float4*)(W + h);
        float4 x = *(const float4*)(&v[wv][h]);
        acc += w.x * x.x + w.y * x.y + w.z * x.z + w.w * x.w;
    }
    float logit = acc + blin[c * Vdim + lane];

    float extra = 0.0f;
    if (lane < 7) {
        const float* We = (lane < 2) ? (Wec + (size_t)lane * Hdim) : (Wrel + (size_t)(lane - 2) * Hdim);
        float a2 = 0.0f;
        for (int h = 0; h < Hdim; h += 4) {
            float4 w = *(const float4*)(We + h);
            float4 x = *(const float4*)(&v[wv][h]);
            a2 += w.x * x.x + w.y * x.y + w.z * x.z + w.w * x.w;
        }
        extra = a2;
    }

    float m = logit;
    for (int s = 32; s >= 1; s >>= 1) m = fmaxf(m, __shfl_xor(m, s));
    float ssum = expf(logit - m);
    for (int s = 32; s >= 1; s >>= 1) ssum += __shfl_xor(ssum, s);
    float lt = __shfl(logit, true_idx[row]);
    float loss = m + logf(ssum) - lt;

    float e0 = __shfl(extra, 0), e1 = __shfl(extra, 1), e2 = __shfl(extra, 2);
    float e3 = __shfl(extra, 3), e4 = __shfl(extra, 4), e5 = __shfl(extra, 5), e6 = __shfl(extra, 6);

    if (lane == 0) {
        float l0 = e0 + bec[0], l1 = e1 + bec[1];
        float me = fmaxf(l0, l1);
        float lse = me + logf(expf(l0 - me) + expf(l1 - me));
        loss += lse - ((ec_idx[row] == 0) ? l0 : l1);
        float r[5] = { e2 + brel[0], e3 + brel[1], e4 + brel[2], e5 + brel[3], e6 + brel[4] };
        float mr = r[0];
        #pragma unroll
        for (int i = 1; i < 5; i++) mr = fmaxf(mr, r[i]);
        float sr = 0.0f;
        #pragma unroll
        for (int i = 0; i < 5; i++) sr += expf(r[i] - mr);
        loss += mr + logf(sr) - r[rel_idx[row]];
        out[(size_t)row * OUTS] = loss;
    }
}

// ---------------- LSTM via bf16 MFMA, fragments loaded DIRECT from global ----------------
// No LDS, no barriers. Block = 4 waves; wave w covers h = hb0 + w*16 + l15, all 4 gates.
// A frag: lane holds X[m=l15][k=quad*8+j] -> 32B contiguous fp32 from X row.
// B frag: lane holds W[n=l15][k=quad*8+j] -> 32B contiguous fp32 from W row.
__global__ __launch_bounds__(256) void k_lstm_mfma(
    const float* __restrict__ inp, const float* __restrict__ h_prev, const float* __restrict__ c_prev,
    const float* __restrict__ W_ih, const float* __restrict__ b_ih,
    const float* __restrict__ W_hh, const float* __restrict__ b_hh,
    const int* __restrict__ perm, const int* __restrict__ tlist,
    float* __restrict__ out)
{
    int blk = blockIdx.x;
    int k = tlist[3 * blk];
    if (k < 0) return;
    int sr = tlist[3 * blk + 1];
    int start = sr & 0xFFFF;
    int rcount = sr >> 16;
    int hb0 = tlist[3 * blk + 2];

    int t = threadIdx.x;
    int w = t >> 6, l = t & 63;
    int l15 = l & 15, quad = l >> 4;

    int row0 = perm[start + min(l15, rcount - 1)];
    int row1 = perm[start + min(l15 + 16, rcount - 1)];
    int h = hb0 + w * 16 + l15;

    const float* Wih_k = W_ih + (size_t)k * G4H * Edim;
    const float* Whh_k = W_hh + (size_t)k * G4H * Hdim;

    const float* wA0 = Wih_k + (size_t)(0 * Hdim + h) * Edim + quad * 8;
    const float* wA1 = Wih_k + (size_t)(1 * Hdim + h) * Edim + quad * 8;
    const float* wA2 = Wih_k + (size_t)(2 * Hdim + h) * Edim + quad * 8;
    const float* wA3 = Wih_k + (size_t)(3 * Hdim + h) * Edim + quad * 8;
    const float* wB0 = Whh_k + (size_t)(0 * Hdim + h) * Hdim + quad * 8;
    const float* wB1 = Whh_k + (size_t)(1 * Hdim + h) * Hdim + quad * 8;
    const float* wB2 = Whh_k + (size_t)(2 * Hdim + h) * Hdim + quad * 8;
    const float* wB3 = Whh_k + (size_t)(3 * Hdim + h) * Hdim + quad * 8;

    const float* xA0 = inp + (size_t)row0 * Edim + quad * 8;
    const float* xA1 = inp + (size_t)row1 * Edim + quad * 8;
    const float* xB0 = h_prev + (size_t)row0 * Hdim + quad * 8;
    const float* xB1 = h_prev + (size_t)row1 * Hdim + quad * 8;

    f32x4 acc[2][4];
    #pragma unroll
    for (int m = 0; m < 2; m++)
        #pragma unroll
        for (int g = 0; g < 4; g++)
            acc[m][g] = (f32x4){0.f, 0.f, 0.f, 0.f};

    // phase A: k in [0,128) over inp / W_ih
    #pragma unroll
    for (int s = 0; s < 4; s++) {
        int ko = s * 32;
        bf16x8 a0 = cvt8(*(const float4*)(xA0 + ko), *(const float4*)(xA0 + ko + 4));
        bf16x8 a1 = cvt8(*(const float4*)(xA1 + ko), *(const float4*)(xA1 + ko + 4));
        bf16x8 b0 = cvt8(*(const float4*)(wA0 + ko), *(const float4*)(wA0 + ko + 4));
        bf16x8 b1 = cvt8(*(const float4*)(wA1 + ko), *(const float4*)(wA1 + ko + 4));
        bf16x8 b2 = cvt8(*(const float4*)(wA2 + ko), *(const float4*)(wA2 + ko + 4));
        bf16x8 b3 = cvt8(*(const float4*)(wA3 + ko), *(const float4*)(wA3 + ko + 4));
        acc[0][0] = __builtin_amdgcn_mfma_f32_16x16x32_bf16(a0, b0, acc[0][0], 0, 0, 0);
        acc[0][1] = __builtin_amdgcn_mfma_f32_16x16x32_bf16(a0, b1, acc[0][1], 0, 0, 0);
        acc[0][2] = __builtin_amdgcn_mfma_f32_16x16x32_bf16(a0, b2, acc[0][2], 0, 0, 0);
        acc[0][3] = __builtin_amdgcn_mfma_f32_16x16x32_bf16(a0, b3, acc[0][3], 0, 0, 0);
        acc[1][0] = __builtin_amdgcn_mfma_f32_16x16x32_bf16(a1, b0, acc[1][0], 0, 0, 0);
        acc[1][1] = __builtin_amdgcn_mfma_f32_16x16x32_bf16(a1, b1, acc[1][1], 0, 0, 0);
        acc[1][2] = __builtin_amdgcn_mfma_f32_16x16x32_bf16(a1, b2, acc[1][2], 0, 0, 0);
        acc[1][3] = __builtin_amdgcn_mfma_f32_16x16x32_bf16(a1, b3, acc[1][3], 0, 0, 0);
    }
    // phase B: k in [128,384) over h_prev / W_hh
    #pragma unroll
    for (int s = 0; s < 8; s++) {
        int ko = s * 32;
        bf16x8 a0 = cvt8(*(const float4*)(xB0 + ko), *(const float4*)(xB0 + ko + 4));
        bf16x8 a1 = cvt8(*(const float4*)(xB1 + ko), *(const float4*)(xB1 + ko + 4));
        bf16x8 b0 = cvt8(*(const float4*)(wB0 + ko), *(const float4*)(wB0 + ko + 4));
        bf16x8 b1 = cvt8(*(const float4*)(wB1 + ko), *(const float4*)(wB1 + ko + 4));
        bf16x8 b2 = cvt8(*(const float4*)(wB2 + ko), *(const float4*)(wB2 + ko + 4));
        bf16x8 b3 = cvt8(*(const float4*)(wB3 + ko), *(const float4*)(wB3 + ko + 4));
        acc[0][0] = __builtin_amdgcn_mfma_f32_16x16x32_bf16(a0, b0, acc[0][0], 0, 0, 0);
        acc[0][1] = __builtin_amdgcn_mfma_f32_16x16x32_bf16(a0, b1, acc[0][1], 0, 0, 0);
        acc[0][2] = __builtin_amdgcn_mfma_f32_16x16x32_bf16(a0, b2, acc[0][2], 0, 0, 0);
        acc[0][3] = __builtin_amdgcn_mfma_f32_16x16x32_bf16(a0, b3, acc[0][3], 0, 0, 0);
        acc[1][0] = __builtin_amdgcn_mfma_f32_16x16x32_bf16(a1, b0, acc[1][0], 0, 0, 0);
        acc[1][1] = __builtin_amdgcn_mfma_f32_16x16x32_bf16(a1, b1, acc[1][1], 0, 0, 0);
        acc[1][2] = __builtin_amdgcn_mfma_f32_16x16x32_bf16(a1, b2, acc[1][2], 0, 0, 0);
        acc[1][3] = __builtin_amdgcn_mfma_f32_16x16x32_bf16(a1, b3, acc[1][3], 0, 0, 0);
    }

    float bsum[4];
    #pragma unroll
    for (int g = 0; g < 4; g++)
        bsum[g] = b_ih[(size_t)k * G4H + g * Hdim + h] + b_hh[(size_t)k * G4H + g * Hdim + h];

    #pragma unroll
    for (int m = 0; m < 2; m++) {
        #pragma unroll
        for (int reg = 0; reg < 4; reg++) {
            int r = m * 16 + quad * 4 + reg;
            if (r < rcount) {
                int row = perm[start + r];
                float iv = acc[m][0][reg] + bsum[0];
                float fv = acc[m][1][reg] + bsum[1];
                float gv = acc[m][2][reg] + bsum[2];
                float ov = acc[m][3][reg] + bsum[3];
                float cp = c_prev[(size_t)row * Hdim + h];
                float cn = sigmoidf_(fv) * cp + sigmoidf_(iv) * tanhf(gv);
                float hn = sigmoidf_(ov) * tanhf(cn);
                out[(size_t)row * OUTS + 1 + h] = hn;
                out[(size_t)row * OUTS + 1 + Hdim + h] = cn;
            }
        }
    }
}

extern "C" void kernel_launch(void* const* d_in, const int* in_sizes, int n_in,
                              void* d_out, int out_size, void* d_ws, size_t ws_size,
                              hipStream_t stream) {
    const float* vec      = (const float*)d_in[0];
    const float* inp      = (const float*)d_in[1];
    const float* h_prev   = (const float*)d_in[2];
    const float* c_prev   = (const float*)d_in[3];
    const float* Wlin     = (const float*)d_in[4];
    const float* blin     = (const float*)d_in[5];
    const float* Wec      = (const float*)d_in[6];
    const float* bec      = (const float*)d_in[7];
    const float* Wrel     = (const float*)d_in[8];
    const float* brel     = (const float*)d_in[9];
    const float* W_ih     = (const float*)d_in[10];
    const float* b_ih     = (const float*)d_in[11];
    const float* W_hh     = (const float*)d_in[12];
    const float* b_hh     = (const float*)d_in[13];
    const int*   category = (const int*)d_in[14];
    const int*   cell_id  = (const int*)d_in[15];
    const int*   true_idx = (const int*)d_in[16];
    const int*   ec_idx   = (const int*)d_in[17];
    const int*   rel_idx  = (const int*)d_in[18];
    float* out = (float*)d_out;

    int* perm  = (int*)d_ws;           // 4096 ints
    int* tlist = perm + Nn;            // 3 * MAXG ints

    k_bucket<<<1, 1024, 0, stream>>>(cell_id, perm, tlist);

    k_loss<<<Nn / 4, 256, 0, stream>>>(vec, Wlin, blin, Wec, bec, Wrel, brel,
                                       category, true_idx, ec_idx, rel_idx, out);

    k_lstm_mfma<<<MAXG, 256, 0, stream>>>(inp, h_prev, c_prev, W_ih, b_ih, W_hh, b_hh,
                                          perm, tlist, out);
}

// Round 4
// 220.237 us; speedup vs baseline: 1.3662x; 1.3662x over previous
//
#include <hip/hip_runtime.h>
#include <hip/hip_bf16.h>
#include <math.h>

#define Nn 4096
#define Hdim 256
#define Edim 128
#define Cdim 32
#define Vdim 64
#define Kdim 20
#define G4H 1024
#define OUTS 513

#define Rr 32            // rows per GEMM tile
#define NB 8             // XCD buckets
#define LMAX 160         // max tiles per bucket (worst case ~147)
#define MAXG (NB * LMAX) // 1280 blocks

typedef short bf16x8 __attribute__((ext_vector_type(8)));
typedef float f32x4 __attribute__((ext_vector_type(4)));

__device__ __forceinline__ float sigmoidf_(float x) { return 1.0f / (1.0f + expf(-x)); }

__device__ __forceinline__ bf16x8 cvt8(float4 f0, float4 f1) {
    bf16x8 r;
    __hip_bfloat16 h;
    h = __float2bfloat16(f0.x); r[0] = *(short*)&h;
    h = __float2bfloat16(f0.y); r[1] = *(short*)&h;
    h = __float2bfloat16(f0.z); r[2] = *(short*)&h;
    h = __float2bfloat16(f0.w); r[3] = *(short*)&h;
    h = __float2bfloat16(f1.x); r[4] = *(short*)&h;
    h = __float2bfloat16(f1.y); r[5] = *(short*)&h;
    h = __float2bfloat16(f1.z); r[6] = *(short*)&h;
    h = __float2bfloat16(f1.w); r[7] = *(short*)&h;
    return r;
}

// ---------------- bucketing: histogram + scan + scatter + PARALLEL tile list ----------------
// tlist entry i (3 ints): [k or -1] [start | rcount<<16] [hb0]
// unit u = k*4 + hb  (80 units); bucket = u % 8; all row-tiles of a unit share a bucket
// slot = (bucket_prefix + s) * 8 + bucket  -> blockIdx % 8 ~ XCD locality
__global__ __launch_bounds__(256) void k_bucket(const int* __restrict__ cell_id,
                                                int* __restrict__ perm,
                                                int* __restrict__ tlist) {
    __shared__ int cnt[Kdim], off[Kdim], cur[Kdim], tk[Kdim];
    int t = threadIdx.x;
    if (t < Kdim) cnt[t] = 0;
    __syncthreads();
    for (int i = t; i < Nn; i += 256) atomicAdd(&cnt[cell_id[i]], 1);
    __syncthreads();
    if (t == 0) {
        int acc = 0;
        for (int k = 0; k < Kdim; k++) {
            off[k] = acc; cur[k] = acc;
            tk[k] = (cnt[k] + Rr - 1) / Rr;
            acc += cnt[k];
        }
    }
    __syncthreads();
    for (int i = t; i < Nn; i += 256) {
        int p = atomicAdd(&cur[cell_id[i]], 1);
        perm[p] = i;
    }
    for (int i = t; i < MAXG; i += 256) tlist[3 * i] = -1;   // ws re-poisoned each call
    // parallel tile-list fill: one thread per (k,hb) unit
    if (t < Kdim * 4) {
        int u = t;
        int k = u >> 2, hb = u & 3;
        int b = u & 7;
        int base = 0;
        for (int v = b; v < u; v += NB) base += tk[v >> 2];   // prefix within bucket
        int c = cnt[k], o = off[k], n = tk[k];
        for (int s = 0; s < n; s++) {
            int slot = (base + s) * NB + b;
            if (slot < MAXG) {
                int rc = min(Rr, c - s * Rr);
                tlist[3 * slot + 0] = k;
                tlist[3 * slot + 1] = (o + s * Rr) | (rc << 16);
                tlist[3 * slot + 2] = hb * 64;
            }
        }
    }
}

// ---------------- loss kernel: 4 waves/block, one row per wave ----------------
__global__ __launch_bounds__(256) void k_loss(
    const float* __restrict__ vec,
    const float* __restrict__ Wlin, const float* __restrict__ blin,
    const float* __restrict__ Wec, const float* __restrict__ bec,
    const float* __restrict__ Wrel, const float* __restrict__ brel,
    const int* __restrict__ category, const int* __restrict__ true_idx,
    const int* __restrict__ ec_idx, const int* __restrict__ rel_idx,
    float* __restrict__ out)
{
    int wv = threadIdx.x >> 6;
    int lane = threadIdx.x & 63;
    int row = blockIdx.x * 4 + wv;
    __shared__ float v[4][Hdim];

    const float* vr = vec + (size_t)row * Hdim;
    ((float4*)v[wv])[lane] = ((const float4*)vr)[lane];  // wave-private: no barrier needed

    int c = category[row];
    const float* W = Wlin + ((size_t)c * Vdim + lane) * Hdim;
    float acc = 0.0f;
    #pragma unroll 4
    for (int h = 0; h < Hdim; h += 4) {
        float4 w = *(const float4*)(W + h);
        float4 x = *(const float4*)(&v[wv][h]);
        acc += w.x * x.x + w.y * x.y + w.z * x.z + w.w * x.w;
    }
    float logit = acc + blin[c * Vdim + lane];

    float extra = 0.0f;
    if (lane < 7) {
        const float* We = (lane < 2) ? (Wec + (size_t)lane * Hdim) : (Wrel + (size_t)(lane - 2) * Hdim);
        float a2 = 0.0f;
        for (int h = 0; h < Hdim; h += 4) {
            float4 w = *(const float4*)(We + h);
            float4 x = *(const float4*)(&v[wv][h]);
            a2 += w.x * x.x + w.y * x.y + w.z * x.z + w.w * x.w;
        }
        extra = a2;
    }

    float m = logit;
    for (int s = 32; s >= 1; s >>= 1) m = fmaxf(m, __shfl_xor(m, s));
    float ssum = expf(logit - m);
    for (int s = 32; s >= 1; s >>= 1) ssum += __shfl_xor(ssum, s);
    float lt = __shfl(logit, true_idx[row]);
    float loss = m + logf(ssum) - lt;

    float e0 = __shfl(extra, 0), e1 = __shfl(extra, 1), e2 = __shfl(extra, 2);
    float e3 = __shfl(extra, 3), e4 = __shfl(extra, 4), e5 = __shfl(extra, 5), e6 = __shfl(extra, 6);

    if (lane == 0) {
        float l0 = e0 + bec[0], l1 = e1 + bec[1];
        float me = fmaxf(l0, l1);
        float lse = me + logf(expf(l0 - me) + expf(l1 - me));
        loss += lse - ((ec_idx[row] == 0) ? l0 : l1);
        float r[5] = { e2 + brel[0], e3 + brel[1], e4 + brel[2], e5 + brel[3], e6 + brel[4] };
        float mr = r[0];
        #pragma unroll
        for (int i = 1; i < 5; i++) mr = fmaxf(mr, r[i]);
        float sr = 0.0f;
        #pragma unroll
        for (int i = 0; i < 5; i++) sr += expf(r[i] - mr);
        loss += mr + logf(sr) - r[rel_idx[row]];
        out[(size_t)row * OUTS] = loss;
    }
}

// ---------------- LSTM via bf16 MFMA, fragments loaded DIRECT from global ----------------
__global__ __launch_bounds__(256) void k_lstm_mfma(
    const float* __restrict__ inp, const float* __restrict__ h_prev, const float* __restrict__ c_prev,
    const float* __restrict__ W_ih, const float* __restrict__ b_ih,
    const float* __restrict__ W_hh, const float* __restrict__ b_hh,
    const int* __restrict__ perm, const int* __restrict__ tlist,
    float* __restrict__ out)
{
    int blk = blockIdx.x;
    int k = tlist[3 * blk];
    if (k < 0) return;
    int sr = tlist[3 * blk + 1];
    int start = sr & 0xFFFF;
    int rcount = sr >> 16;
    int hb0 = tlist[3 * blk + 2];

    int t = threadIdx.x;
    int w = t >> 6, l = t & 63;
    int l15 = l & 15, quad = l >> 4;

    int row0 = perm[start + min(l15, rcount - 1)];
    int row1 = perm[start + min(l15 + 16, rcount - 1)];
    int h = hb0 + w * 16 + l15;

    const float* Wih_k = W_ih + (size_t)k * G4H * Edim;
    const float* Whh_k = W_hh + (size_t)k * G4H * Hdim;

    const float* wA0 = Wih_k + (size_t)(0 * Hdim + h) * Edim + quad * 8;
    const float* wA1 = Wih_k + (size_t)(1 * Hdim + h) * Edim + quad * 8;
    const float* wA2 = Wih_k + (size_t)(2 * Hdim + h) * Edim + quad * 8;
    const float* wA3 = Wih_k + (size_t)(3 * Hdim + h) * Edim + quad * 8;
    const float* wB0 = Whh_k + (size_t)(0 * Hdim + h) * Hdim + quad * 8;
    const float* wB1 = Whh_k + (size_t)(1 * Hdim + h) * Hdim + quad * 8;
    const float* wB2 = Whh_k + (size_t)(2 * Hdim + h) * Hdim + quad * 8;
    const float* wB3 = Whh_k + (size_t)(3 * Hdim + h) * Hdim + quad * 8;

    const float* xA0 = inp + (size_t)row0 * Edim + quad * 8;
    const float* xA1 = inp + (size_t)row1 * Edim + quad * 8;
    const float* xB0 = h_prev + (size_t)row0 * Hdim + quad * 8;
    const float* xB1 = h_prev + (size_t)row1 * Hdim + quad * 8;

    f32x4 acc[2][4];
    #pragma unroll
    for (int m = 0; m < 2; m++)
        #pragma unroll
        for (int g = 0; g < 4; g++)
            acc[m][g] = (f32x4){0.f, 0.f, 0.f, 0.f};

    // phase A: k in [0,128) over inp / W_ih
    #pragma unroll
    for (int s = 0; s < 4; s++) {
        int ko = s * 32;
        bf16x8 a0 = cvt8(*(const float4*)(xA0 + ko), *(const float4*)(xA0 + ko + 4));
        bf16x8 a1 = cvt8(*(const float4*)(xA1 + ko), *(const float4*)(xA1 + ko + 4));
        bf16x8 b0 = cvt8(*(const float4*)(wA0 + ko), *(const float4*)(wA0 + ko + 4));
        bf16x8 b1 = cvt8(*(const float4*)(wA1 + ko), *(const float4*)(wA1 + ko + 4));
        bf16x8 b2 = cvt8(*(const float4*)(wA2 + ko), *(const float4*)(wA2 + ko + 4));
        bf16x8 b3 = cvt8(*(const float4*)(wA3 + ko), *(const float4*)(wA3 + ko + 4));
        acc[0][0] = __builtin_amdgcn_mfma_f32_16x16x32_bf16(a0, b0, acc[0][0], 0, 0, 0);
        acc[0][1] = __builtin_amdgcn_mfma_f32_16x16x32_bf16(a0, b1, acc[0][1], 0, 0, 0);
        acc[0][2] = __builtin_amdgcn_mfma_f32_16x16x32_bf16(a0, b2, acc[0][2], 0, 0, 0);
        acc[0][3] = __builtin_amdgcn_mfma_f32_16x16x32_bf16(a0, b3, acc[0][3], 0, 0, 0);
        acc[1][0] = __builtin_amdgcn_mfma_f32_16x16x32_bf16(a1, b0, acc[1][0], 0, 0, 0);
        acc[1][1] = __builtin_amdgcn_mfma_f32_16x16x32_bf16(a1, b1, acc[1][1], 0, 0, 0);
        acc[1][2] = __builtin_amdgcn_mfma_f32_16x16x32_bf16(a1, b2, acc[1][2], 0, 0, 0);
        acc[1][3] = __builtin_amdgcn_mfma_f32_16x16x32_bf16(a1, b3, acc[1][3], 0, 0, 0);
    }
    // phase B: k in [128,384) over h_prev / W_hh
    #pragma unroll
    for (int s = 0; s < 8; s++) {
        int ko = s * 32;
        bf16x8 a0 = cvt8(*(const float4*)(xB0 + ko), *(const float4*)(xB0 + ko + 4));
        bf16x8 a1 = cvt8(*(const float4*)(xB1 + ko), *(const float4*)(xB1 + ko + 4));
        bf16x8 b0 = cvt8(*(const float4*)(wB0 + ko), *(const float4*)(wB0 + ko + 4));
        bf16x8 b1 = cvt8(*(const float4*)(wB1 + ko), *(const float4*)(wB1 + ko + 4));
        bf16x8 b2 = cvt8(*(const float4*)(wB2 + ko), *(const float4*)(wB2 + ko + 4));
        bf16x8 b3 = cvt8(*(const float4*)(wB3 + ko), *(const float4*)(wB3 + ko + 4));
        acc[0][0] = __builtin_amdgcn_mfma_f32_16x16x32_bf16(a0, b0, acc[0][0], 0, 0, 0);
        acc[0][1] = __builtin_amdgcn_mfma_f32_16x16x32_bf16(a0, b1, acc[0][1], 0, 0, 0);
        acc[0][2] = __builtin_amdgcn_mfma_f32_16x16x32_bf16(a0, b2, acc[0][2], 0, 0, 0);
        acc[0][3] = __builtin_amdgcn_mfma_f32_16x16x32_bf16(a0, b3, acc[0][3], 0, 0, 0);
        acc[1][0] = __builtin_amdgcn_mfma_f32_16x16x32_bf16(a1, b0, acc[1][0], 0, 0, 0);
        acc[1][1] = __builtin_amdgcn_mfma_f32_16x16x32_bf16(a1, b1, acc[1][1], 0, 0, 0);
        acc[1][2] = __builtin_amdgcn_mfma_f32_16x16x32_bf16(a1, b2, acc[1][2], 0, 0, 0);
        acc[1][3] = __builtin_amdgcn_mfma_f32_16x16x32_bf16(a1, b3, acc[1][3], 0, 0, 0);
    }

    float bsum[4];
    #pragma unroll
    for (int g = 0; g < 4; g++)
        bsum[g] = b_ih[(size_t)k * G4H + g * Hdim + h] + b_hh[(size_t)k * G4H + g * Hdim + h];

    #pragma unroll
    for (int m = 0; m < 2; m++) {
        #pragma unroll
        for (int reg = 0; reg < 4; reg++) {
            int r = m * 16 + quad * 4 + reg;
            if (r < rcount) {
                int row = perm[start + r];
                float iv = acc[m][0][reg] + bsum[0];
                float fv = acc[m][1][reg] + bsum[1];
                float gv = acc[m][2][reg] + bsum[2];
                float ov = acc[m][3][reg] + bsum[3];
                float cp = c_prev[(size_t)row * Hdim + h];
                float cn = sigmoidf_(fv) * cp + sigmoidf_(iv) * tanhf(gv);
                float hn = sigmoidf_(ov) * tanhf(cn);
                out[(size_t)row * OUTS + 1 + h] = hn;
                out[(size_t)row * OUTS + 1 + Hdim + h] = cn;
            }
        }
    }
}

extern "C" void kernel_launch(void* const* d_in, const int* in_sizes, int n_in,
                              void* d_out, int out_size, void* d_ws, size_t ws_size,
                              hipStream_t stream) {
    const float* vec      = (const float*)d_in[0];
    const float* inp      = (const float*)d_in[1];
    const float* h_prev   = (const float*)d_in[2];
    const float* c_prev   = (const float*)d_in[3];
    const float* Wlin     = (const float*)d_in[4];
    const float* blin     = (const float*)d_in[5];
    const float* Wec      = (const float*)d_in[6];
    const float* bec      = (const float*)d_in[7];
    const float* Wrel     = (const float*)d_in[8];
    const float* brel     = (const float*)d_in[9];
    const float* W_ih     = (const float*)d_in[10];
    const float* b_ih     = (const float*)d_in[11];
    const float* W_hh     = (const float*)d_in[12];
    const float* b_hh     = (const float*)d_in[13];
    const int*   category = (const int*)d_in[14];
    const int*   cell_id  = (const int*)d_in[15];
    const int*   true_idx = (const int*)d_in[16];
    const int*   ec_idx   = (const int*)d_in[17];
    const int*   rel_idx  = (const int*)d_in[18];
    float* out = (float*)d_out;

    int* perm  = (int*)d_ws;           // 4096 ints
    int* tlist = perm + Nn;            // 3 * MAXG ints

    k_bucket<<<1, 256, 0, stream>>>(cell_id, perm, tlist);

    k_loss<<<Nn / 4, 256, 0, stream>>>(vec, Wlin, blin, Wec, bec, Wrel, brel,
                                       category, true_idx, ec_idx, rel_idx, out);

    k_lstm_mfma<<<MAXG, 256, 0, stream>>>(inp, h_prev, c_prev, W_ih, b_ih, W_hh, b_hh,
                                          perm, tlist, out);
}

// Round 5
// 190.707 us; speedup vs baseline: 1.5777x; 1.1548x over previous
//
#include <hip/hip_runtime.h>
#include <hip/hip_bf16.h>
#include <math.h>

#define Nn 4096
#define Hdim 256
#define Edim 128
#define Cdim 32
#define Vdim 64
#define Kdim 20
#define G4H 1024
#define OUTS 513

#define Rr 32            // rows per GEMM tile
#define NB 8             // XCD buckets
#define LMAX 160         // max tiles per bucket (worst case 137)
#define MAXG (NB * LMAX) // 1280 lstm block slots
#define LOSSB (Nn / 4)   // 1024 loss blocks

typedef short bf16x8 __attribute__((ext_vector_type(8)));
typedef float f32x4 __attribute__((ext_vector_type(4)));

__device__ __forceinline__ float sigmoidf_(float x) { return 1.0f / (1.0f + expf(-x)); }

__device__ __forceinline__ bf16x8 cvt8(float4 f0, float4 f1) {
    bf16x8 r;
    __hip_bfloat16 h;
    h = __float2bfloat16(f0.x); r[0] = *(short*)&h;
    h = __float2bfloat16(f0.y); r[1] = *(short*)&h;
    h = __float2bfloat16(f0.z); r[2] = *(short*)&h;
    h = __float2bfloat16(f0.w); r[3] = *(short*)&h;
    h = __float2bfloat16(f1.x); r[4] = *(short*)&h;
    h = __float2bfloat16(f1.y); r[5] = *(short*)&h;
    h = __float2bfloat16(f1.z); r[6] = *(short*)&h;
    h = __float2bfloat16(f1.w); r[7] = *(short*)&h;
    return r;
}

// async global->LDS, 16B per lane; LDS dest = base (wave-uniform) + lane*16
__device__ __forceinline__ void gl_lds16(const float* g, float* l) {
    __builtin_amdgcn_global_load_lds((const __attribute__((address_space(1))) void*)g,
                                     (__attribute__((address_space(3))) void*)l, 16, 0, 0);
}

// ---------------- bucketing (unchanged from r4) ----------------
__global__ __launch_bounds__(256) void k_bucket(const int* __restrict__ cell_id,
                                                int* __restrict__ perm,
                                                int* __restrict__ tlist) {
    __shared__ int cnt[Kdim], off[Kdim], cur[Kdim], tk[Kdim];
    int t = threadIdx.x;
    if (t < Kdim) cnt[t] = 0;
    __syncthreads();
    for (int i = t; i < Nn; i += 256) atomicAdd(&cnt[cell_id[i]], 1);
    __syncthreads();
    if (t == 0) {
        int acc = 0;
        for (int k = 0; k < Kdim; k++) {
            off[k] = acc; cur[k] = acc;
            tk[k] = (cnt[k] + Rr - 1) / Rr;
            acc += cnt[k];
        }
    }
    __syncthreads();
    for (int i = t; i < Nn; i += 256) {
        int p = atomicAdd(&cur[cell_id[i]], 1);
        perm[p] = i;
    }
    for (int i = t; i < MAXG; i += 256) tlist[3 * i] = -1;
    if (t < Kdim * 4) {
        int u = t;
        int k = u >> 2, hb = u & 3;
        int b = u & 7;
        int base = 0;
        for (int v = b; v < u; v += NB) base += tk[v >> 2];
        int c = cnt[k], o = off[k], n = tk[k];
        for (int s = 0; s < n; s++) {
            int slot = (base + s) * NB + b;
            if (slot < MAXG) {
                int rc = min(Rr, c - s * Rr);
                tlist[3 * slot + 0] = k;
                tlist[3 * slot + 1] = (o + s * Rr) | (rc << 16);
                tlist[3 * slot + 2] = hb * 64;
            }
        }
    }
}

// ---------------- fused main kernel: lstm blocks [0,MAXG), loss blocks [MAXG, MAXG+LOSSB) ----------------
__global__ __launch_bounds__(256, 4) void k_main(
    const float* __restrict__ vec,
    const float* __restrict__ inp, const float* __restrict__ h_prev, const float* __restrict__ c_prev,
    const float* __restrict__ Wlin, const float* __restrict__ blin,
    const float* __restrict__ Wec, const float* __restrict__ bec,
    const float* __restrict__ Wrel, const float* __restrict__ brel,
    const float* __restrict__ W_ih, const float* __restrict__ b_ih,
    const float* __restrict__ W_hh, const float* __restrict__ b_hh,
    const int* __restrict__ category, const int* __restrict__ true_idx,
    const int* __restrict__ ec_idx, const int* __restrict__ rel_idx,
    const int* __restrict__ perm, const int* __restrict__ tlist,
    float* __restrict__ out)
{
    __shared__ float smem[9216];   // 36 KB: Wbuf[256][32] (32KB) + Xbuf[32][32] (4KB)
    int t = threadIdx.x;

    if (blockIdx.x >= MAXG) {
        // ================= loss branch =================
        int wv = t >> 6;
        int lane = t & 63;
        int row = (blockIdx.x - MAXG) * 4 + wv;
        float* v = smem + wv * Hdim;

        const float* vr = vec + (size_t)row * Hdim;
        ((float4*)v)[lane] = ((const float4*)vr)[lane];   // wave-private, no barrier

        int c = category[row];
        const float* W = Wlin + ((size_t)c * Vdim + lane) * Hdim;
        float acc = 0.0f;
        #pragma unroll 8
        for (int h = 0; h < Hdim; h += 4) {
            float4 w = *(const float4*)(W + h);
            float4 x = *(const float4*)(v + h);
            acc += w.x * x.x + w.y * x.y + w.z * x.z + w.w * x.w;
        }
        float logit = acc + blin[c * Vdim + lane];

        float extra = 0.0f;
        if (lane < 7) {
            const float* We = (lane < 2) ? (Wec + (size_t)lane * Hdim) : (Wrel + (size_t)(lane - 2) * Hdim);
            float a2 = 0.0f;
            for (int h = 0; h < Hdim; h += 4) {
                float4 w = *(const float4*)(We + h);
                float4 x = *(const float4*)(v + h);
                a2 += w.x * x.x + w.y * x.y + w.z * x.z + w.w * x.w;
            }
            extra = a2;
        }

        float m = logit;
        for (int s = 32; s >= 1; s >>= 1) m = fmaxf(m, __shfl_xor(m, s));
        float ssum = expf(logit - m);
        for (int s = 32; s >= 1; s >>= 1) ssum += __shfl_xor(ssum, s);
        float lt = __shfl(logit, true_idx[row]);
        float loss = m + logf(ssum) - lt;

        float e0 = __shfl(extra, 0), e1 = __shfl(extra, 1), e2 = __shfl(extra, 2);
        float e3 = __shfl(extra, 3), e4 = __shfl(extra, 4), e5 = __shfl(extra, 5), e6 = __shfl(extra, 6);

        if (lane == 0) {
            float l0 = e0 + bec[0], l1 = e1 + bec[1];
            float me = fmaxf(l0, l1);
            float lse = me + logf(expf(l0 - me) + expf(l1 - me));
            loss += lse - ((ec_idx[row] == 0) ? l0 : l1);
            float r[5] = { e2 + brel[0], e3 + brel[1], e4 + brel[2], e5 + brel[3], e6 + brel[4] };
            float mr = r[0];
            #pragma unroll
            for (int i = 1; i < 5; i++) mr = fmaxf(mr, r[i]);
            float sr = 0.0f;
            #pragma unroll
            for (int i = 0; i < 5; i++) sr += expf(r[i] - mr);
            loss += mr + logf(sr) - r[rel_idx[row]];
            out[(size_t)row * OUTS] = loss;
        }
        return;
    }

    // ================= lstm branch =================
    int blk = blockIdx.x;
    int k = tlist[3 * blk];
    if (k < 0) return;
    int sr = tlist[3 * blk + 1];
    int start = sr & 0xFFFF;
    int rcount = sr >> 16;
    int hb0 = tlist[3 * blk + 2];

    int w = t >> 6, l = t & 63;
    int l15 = l & 15, quad = l >> 4;
    int lrow8 = l >> 3;     // 0..7 : row-within-instr for staging
    int lslot = l & 7;      // 16B slot within 128B LDS row
    int swz_l = ((l15 & 3) << 1) | ((l15 >> 2) & 1);   // read-side swizzle key

    float* Wbuf = smem;           // [256 rows][32 fp32]
    float* Xbuf = smem + 8192;    // [32 rows][32 fp32]

    const float* Wih_k = W_ih + (size_t)k * G4H * Edim;
    const float* Whh_k = W_hh + (size_t)k * G4H * Hdim;

    f32x4 acc[2][4];
    #pragma unroll
    for (int m = 0; m < 2; m++)
        #pragma unroll
        for (int g = 0; g < 4; g++)
            acc[m][g] = (f32x4){0.f, 0.f, 0.f, 0.f};

    int p0 = (quad * 2) ^ swz_l;   // phys slot of logical slot quad*2

    for (int st = 0; st < 12; st++) {
        int k0 = st * 32;
        const float* Wsrc;
        int stride, ko;
        if (k0 < Edim) { Wsrc = Wih_k; stride = Edim; ko = k0; }
        else           { Wsrc = Whh_k; stride = Hdim; ko = k0 - Edim; }

        __syncthreads();    // previous step's reads done before overwrite
        // stage W tile: wave w covers LDS rows [w*64, w*64+64), 8 async instrs
        #pragma unroll
        for (int j = 0; j < 8; j++) {
            int r = w * 64 + j * 8 + lrow8;
            int g = lslot ^ (((r & 3) << 1) | ((r >> 2) & 1));
            int gate = r >> 6, hl = r & 63;
            const float* gp = Wsrc + (size_t)(gate * Hdim + hb0 + hl) * stride + ko + g * 4;
            gl_lds16(gp, Wbuf + (w * 64 + j * 8) * 32);
        }
        // stage X tile: wave w covers rows [w*8, w*8+8), 1 async instr
        {
            int r = w * 8 + lrow8;
            int g = lslot ^ (((r & 3) << 1) | ((r >> 2) & 1));
            int row = perm[start + min(r, rcount - 1)];
            const float* gp = (k0 < Edim ? inp + (size_t)row * Edim + ko
                                         : h_prev + (size_t)row * Hdim + ko) + g * 4;
            gl_lds16(gp, Xbuf + (w * 8) * 32);
        }
        __syncthreads();    // drains vmcnt before barrier -> tiles ready

        bf16x8 af[2], bfr[4];
        #pragma unroll
        for (int m = 0; m < 2; m++) {
            int row = m * 16 + l15;
            float4 lo = *(float4*)(Xbuf + row * 32 + p0 * 4);
            float4 hi = *(float4*)(Xbuf + row * 32 + (p0 ^ 1) * 4);
            af[m] = cvt8(lo, hi);
        }
        #pragma unroll
        for (int g = 0; g < 4; g++) {
            int row = g * 64 + w * 16 + l15;
            float4 lo = *(float4*)(Wbuf + row * 32 + p0 * 4);
            float4 hi = *(float4*)(Wbuf + row * 32 + (p0 ^ 1) * 4);
            bfr[g] = cvt8(lo, hi);
        }
        #pragma unroll
        for (int m = 0; m < 2; m++)
            #pragma unroll
            for (int g = 0; g < 4; g++)
                acc[m][g] = __builtin_amdgcn_mfma_f32_16x16x32_bf16(af[m], bfr[g], acc[m][g], 0, 0, 0);
    }

    int h = hb0 + w * 16 + l15;
    float bsum[4];
    #pragma unroll
    for (int g = 0; g < 4; g++)
        bsum[g] = b_ih[(size_t)k * G4H + g * Hdim + h] + b_hh[(size_t)k * G4H + g * Hdim + h];

    #pragma unroll
    for (int m = 0; m < 2; m++) {
        #pragma unroll
        for (int reg = 0; reg < 4; reg++) {
            int r = m * 16 + quad * 4 + reg;
            if (r < rcount) {
                int row = perm[start + r];
                float iv = acc[m][0][reg] + bsum[0];
                float fv = acc[m][1][reg] + bsum[1];
                float gv = acc[m][2][reg] + bsum[2];
                float ov = acc[m][3][reg] + bsum[3];
                float cp = c_prev[(size_t)row * Hdim + h];
                float cn = sigmoidf_(fv) * cp + sigmoidf_(iv) * tanhf(gv);
                float hn = sigmoidf_(ov) * tanhf(cn);
                out[(size_t)row * OUTS + 1 + h] = hn;
                out[(size_t)row * OUTS + 1 + Hdim + h] = cn;
            }
        }
    }
}

extern "C" void kernel_launch(void* const* d_in, const int* in_sizes, int n_in,
                              void* d_out, int out_size, void* d_ws, size_t ws_size,
                              hipStream_t stream) {
    const float* vec      = (const float*)d_in[0];
    const float* inp      = (const float*)d_in[1];
    const float* h_prev   = (const float*)d_in[2];
    const float* c_prev   = (const float*)d_in[3];
    const float* Wlin     = (const float*)d_in[4];
    const float* blin     = (const float*)d_in[5];
    const float* Wec      = (const float*)d_in[6];
    const float* bec      = (const float*)d_in[7];
    const float* Wrel     = (const float*)d_in[8];
    const float* brel     = (const float*)d_in[9];
    const float* W_ih     = (const float*)d_in[10];
    const float* b_ih     = (const float*)d_in[11];
    const float* W_hh     = (const float*)d_in[12];
    const float* b_hh     = (const float*)d_in[13];
    const int*   category = (const int*)d_in[14];
    const int*   cell_id  = (const int*)d_in[15];
    const int*   true_idx = (const int*)d_in[16];
    const int*   ec_idx   = (const int*)d_in[17];
    const int*   rel_idx  = (const int*)d_in[18];
    float* out = (float*)d_out;

    int* perm  = (int*)d_ws;           // 4096 ints
    int* tlist = perm + Nn;            // 3 * MAXG ints

    k_bucket<<<1, 256, 0, stream>>>(cell_id, perm, tlist);

    k_main<<<MAXG + LOSSB, 256, 0, stream>>>(
        vec, inp, h_prev, c_prev, Wlin, blin, Wec, bec, Wrel, brel,
        W_ih, b_ih, W_hh, b_hh, category, true_idx, ec_idx, rel_idx,
        perm, tlist, out);
}

// Round 6
// 153.567 us; speedup vs baseline: 1.9593x; 1.2418x over previous
//
#include <hip/hip_runtime.h>
#include <hip/hip_bf16.h>
#include <math.h>

#define Nn 4096
#define Hdim 256
#define Edim 128
#define Cdim 32
#define Vdim 64
#define Kdim 20
#define G4H 1024
#define OUTS 513

#define NB 8               // XCD buckets for lstm tiles
#define LMAX 160
#define MAXG (NB * LMAX)   // 1280 lstm slots
#define MAXT2 192          // loss tile slots
#define PRMAX 4736         // padded lstm rows max
#define PR2MAX 5120        // padded loss rows max

// pack segment sizes
#define SEG_A 983040       // lstm W:  80u * 6st * 256r * 8p
#define SEG_B 227328       // Xp:      4736 * 6 * 8
#define SEG_C 163840       // Vp:      5120 * 4 * 8
#define SEG_D 81920        // Wlp:     32 * 4 * 80 * 8
#define SEG_E 20480        // bsum
#define SEG_F 2560         // bl2
#define PACK_T (SEG_A + SEG_B + SEG_C + SEG_D + SEG_E + SEG_F)   // 1,479,168 = 5778*256

typedef short bf16x8 __attribute__((ext_vector_type(8)));
typedef float f32x4 __attribute__((ext_vector_type(4)));

__device__ __forceinline__ float sigmoidf_(float x) { return 1.0f / (1.0f + expf(-x)); }

__device__ __forceinline__ bf16x8 cvt8(float4 f0, float4 f1) {
    bf16x8 r;
    __hip_bfloat16 h;
    h = __float2bfloat16(f0.x); r[0] = *(short*)&h;
    h = __float2bfloat16(f0.y); r[1] = *(short*)&h;
    h = __float2bfloat16(f0.z); r[2] = *(short*)&h;
    h = __float2bfloat16(f0.w); r[3] = *(short*)&h;
    h = __float2bfloat16(f1.x); r[4] = *(short*)&h;
    h = __float2bfloat16(f1.y); r[5] = *(short*)&h;
    h = __float2bfloat16(f1.z); r[6] = *(short*)&h;
    h = __float2bfloat16(f1.w); r[7] = *(short*)&h;
    return r;
}

__device__ __forceinline__ void gl_lds16(const short* g, void* l) {
    __builtin_amdgcn_global_load_lds((const __attribute__((address_space(1))) void*)g,
                                     (__attribute__((address_space(3))) void*)l, 16, 0, 0);
}

// ---------------- bucketing: both keys, padded perms, tile lists ----------------
__global__ __launch_bounds__(1024) void k_bucket(const int* __restrict__ cell_id,
                                                 const int* __restrict__ category,
                                                 int* __restrict__ pperm, int* __restrict__ pperm2,
                                                 int* __restrict__ tlist, int* __restrict__ tlist2,
                                                 int* __restrict__ meta) {
    __shared__ int cnt[Kdim], cur[Kdim], po[Kdim], tk[Kdim];
    __shared__ int cnt2[Cdim], cur2[Cdim], po2[Cdim], tk2[Cdim];
    int t = threadIdx.x;
    if (t < Kdim) cnt[t] = 0;
    if (t < Cdim) cnt2[t] = 0;
    __syncthreads();
    for (int i = t; i < Nn; i += 1024) {
        atomicAdd(&cnt[cell_id[i]], 1);
        atomicAdd(&cnt2[category[i]], 1);
    }
    __syncthreads();
    if (t == 0) {
        int acc = 0;
        for (int k = 0; k < Kdim; k++) { po[k] = acc; cur[k] = acc; tk[k] = (cnt[k] + 31) >> 5; acc += tk[k] * 32; }
        meta[0] = acc;   // PRtot
        acc = 0;
        for (int m = 0; m < Cdim; m++) { po2[m] = acc; cur2[m] = acc; tk2[m] = (cnt2[m] + 31) >> 5; acc += tk2[m] * 32; }
        meta[1] = acc;   // PR2tot
    }
    __syncthreads();
    for (int i = t; i < Nn; i += 1024) {
        int p = atomicAdd(&cur[cell_id[i]], 1);
        pperm[p] = i;
        int p2 = atomicAdd(&cur2[category[i]], 1);
        pperm2[p2] = i;
    }
    for (int i = t; i < MAXG; i += 1024) tlist[3 * i] = -1;
    for (int i = t; i < MAXT2; i += 1024) tlist2[3 * i] = -1;
    __syncthreads();
    // pad fill (duplicate first row of each bucket into the tail pad slots)
    for (int i = t; i < (Kdim + Cdim) * 32; i += 1024) {
        if (i < Kdim * 32) {
            int k = i >> 5, j = i & 31;
            int s = cnt[k] + j;
            if (cnt[k] > 0 && s < tk[k] * 32) pperm[po[k] + s] = pperm[po[k]];
        } else {
            int ii = i - Kdim * 32;
            int m = ii >> 5, j = ii & 31;
            int s = cnt2[m] + j;
            if (cnt2[m] > 0 && s < tk2[m] * 32) pperm2[po2[m] + s] = pperm2[po2[m]];
        }
    }
    // lstm tile list: unit u = k*4+hb -> bucket u%8, interleaved slots
    if (t < Kdim * 4) {
        int u = t, k = u >> 2, hb = u & 3, b = u & 7;
        int base = 0;
        for (int v = b; v < u; v += NB) base += tk[v >> 2];
        int n = tk[k], c = cnt[k];
        for (int s = 0; s < n; s++) {
            int slot = (base + s) * NB + b;
            if (slot < MAXG) {
                int rc = min(32, c - s * 32);
                tlist[3 * slot + 0] = k;
                tlist[3 * slot + 1] = (po[k] >> 5) + s;
                tlist[3 * slot + 2] = (hb * 64) | (rc << 16);
            }
        }
    }
    // loss tile list: sequential
    if (t >= 128 && t < 128 + Cdim) {
        int m = t - 128;
        int base = 0;
        for (int mm = 0; mm < m; mm++) base += tk2[mm];
        int n = tk2[m], c = cnt2[m];
        for (int s = 0; s < n; s++) {
            int slot = base + s;
            if (slot < MAXT2) {
                int rc = min(32, c - s * 32);
                tlist2[3 * slot + 0] = m;
                tlist2[3 * slot + 1] = (po2[m] >> 5) + s;
                tlist2[3 * slot + 2] = rc;
            }
        }
    }
}

// ---------------- pack: bf16-convert everything, swizzle + permute baked in ----------------
// slot swizzle within each 64-elem (128B) LDS row: phys slot p holds logical chunk c = p ^ (row & 7)
__global__ __launch_bounds__(256) void k_pack(
    const float* __restrict__ vec, const float* __restrict__ inp, const float* __restrict__ h_prev,
    const float* __restrict__ Wlin, const float* __restrict__ blin,
    const float* __restrict__ Wec, const float* __restrict__ bec,
    const float* __restrict__ Wrel, const float* __restrict__ brel,
    const float* __restrict__ W_ih, const float* __restrict__ b_ih,
    const float* __restrict__ W_hh, const float* __restrict__ b_hh,
    const int* __restrict__ pperm, const int* __restrict__ pperm2, const int* __restrict__ meta,
    short* __restrict__ Wp, short* __restrict__ Xp, short* __restrict__ Vp, short* __restrict__ Wlp,
    float* __restrict__ bsum, float* __restrict__ bl2)
{
    int tid = blockIdx.x * 256 + threadIdx.x;
    if (tid < SEG_A) {
        // lstm weights: Wp[u][st][r(256)][64], 8 bf16 per thread
        int u = tid / 12288;
        int rem = tid % 12288;
        int st = rem / 2048;
        int rem2 = rem % 2048;
        int r = rem2 >> 3, p = rem2 & 7;
        int k = u >> 2, hb = u & 3;
        int c = p ^ (r & 7);
        int kk = st * 64 + c * 8;
        int grow = (r >> 6) * Hdim + hb * 64 + (r & 63);
        const float* src = (kk < Edim) ? W_ih + ((size_t)k * G4H + grow) * Edim + kk
                                       : W_hh + ((size_t)k * G4H + grow) * Hdim + (kk - Edim);
        float4 f0 = *(const float4*)(src);
        float4 f1 = *(const float4*)(src + 4);
        *(bf16x8*)(Wp + ((size_t)(u * 6 + st) * 256 + r) * 64 + p * 8) = cvt8(f0, f1);
    } else if (tid < SEG_A + SEG_B) {
        // Xp[pb][st][r(32)][64], perm-ordered
        int t2 = tid - SEG_A;
        int i = t2 / 48;
        int rem = t2 % 48;
        int st = rem >> 3, q = rem & 7;
        if (i < meta[0]) {
            int orig = pperm[i];
            int r = i & 31, pb = i >> 5;
            int c = q ^ (r & 7);
            int kk = st * 64 + c * 8;
            const float* src = (kk < Edim) ? inp + (size_t)orig * Edim + kk
                                           : h_prev + (size_t)orig * Hdim + (kk - Edim);
            float4 f0 = *(const float4*)(src);
            float4 f1 = *(const float4*)(src + 4);
            *(bf16x8*)(Xp + (size_t)pb * 12288 + st * 2048 + r * 64 + q * 8) = cvt8(f0, f1);
        }
    } else if (tid < SEG_A + SEG_B + SEG_C) {
        // Vp[pb2][st(4)][r(32)][64], perm2-ordered
        int t3 = tid - SEG_A - SEG_B;
        int j = t3 / 32;
        int rem = t3 % 32;
        int st = rem >> 3, q = rem & 7;
        if (j < meta[1]) {
            int orig = pperm2[j];
            int r = j & 31, pb2 = j >> 5;
            int c = q ^ (r & 7);
            int kk = st * 64 + c * 8;
            const float* src = vec + (size_t)orig * Hdim + kk;
            float4 f0 = *(const float4*)(src);
            float4 f1 = *(const float4*)(src + 4);
            *(bf16x8*)(Vp + (size_t)pb2 * 8192 + st * 2048 + r * 64 + q * 8) = cvt8(f0, f1);
        }
    } else if (tid < SEG_A + SEG_B + SEG_C + SEG_D) {
        // Wlp[m][st(4)][r(80)][64]: rows 0..63 Wlin, 64..65 Wec, 66..70 Wrel, 71..79 zero
        int t4 = tid - SEG_A - SEG_B - SEG_C;
        int m = t4 / 2560;
        int rem = t4 % 2560;
        int st = rem / 640;
        int rem2 = rem % 640;
        int r = rem2 >> 3, q = rem2 & 7;
        int c = q ^ (r & 7);
        int kk = st * 64 + c * 8;
        float4 f0 = {0.f, 0.f, 0.f, 0.f}, f1 = {0.f, 0.f, 0.f, 0.f};
        if (r < 64) {
            const float* src = Wlin + ((size_t)m * Vdim + r) * Hdim + kk;
            f0 = *(const float4*)(src); f1 = *(const float4*)(src + 4);
        } else if (r < 66) {
            const float* src = Wec + (size_t)(r - 64) * Hdim + kk;
            f0 = *(const float4*)(src); f1 = *(const float4*)(src + 4);
        } else if (r < 71) {
            const float* src = Wrel + (size_t)(r - 66) * Hdim + kk;
            f0 = *(const float4*)(src); f1 = *(const float4*)(src + 4);
        }
        *(bf16x8*)(Wlp + (size_t)m * 20480 + st * 5120 + r * 64 + q * 8) = cvt8(f0, f1);
    } else if (tid < SEG_A + SEG_B + SEG_C + SEG_D + SEG_E) {
        int t5 = tid - SEG_A - SEG_B - SEG_C - SEG_D;
        int k = t5 >> 10, rem = t5 & 1023;
        bsum[t5] = b_ih[(size_t)k * G4H + rem] + b_hh[(size_t)k * G4H + rem];
    } else if (tid < PACK_T) {
        int t6 = tid - SEG_A - SEG_B - SEG_C - SEG_D - SEG_E;
        int m = t6 / 80, v = t6 % 80;
        float b = 0.f;
        if (v < 64) b = blin[m * Vdim + v];
        else if (v < 66) b = bec[v - 64];
        else if (v < 71) b = brel[v - 66];
        bl2[t6] = b;
    }
}

// ---------------- fused main: lstm tiles [0,MAXG), loss tiles [MAXG, MAXG+MAXT2) ----------------
__global__ __launch_bounds__(256, 4) void k_main(
    const float* __restrict__ c_prev,
    const short* __restrict__ Wp, const short* __restrict__ Xp,
    const short* __restrict__ Vp, const short* __restrict__ Wlp,
    const float* __restrict__ bsum, const float* __restrict__ bl2,
    const int* __restrict__ pperm, const int* __restrict__ pperm2,
    const int* __restrict__ tlist, const int* __restrict__ tlist2,
    const int* __restrict__ true_idx, const int* __restrict__ ec_idx, const int* __restrict__ rel_idx,
    float* __restrict__ out)
{
    __shared__ __align__(16) char smem[36864];
    int t = threadIdx.x;
    int w = t >> 6, l = t & 63;
    int l15 = l & 15, quad = l >> 4;

    if (blockIdx.x < MAXG) {
        // ============ LSTM tile ============
        int k = tlist[3 * blockIdx.x];
        if (k < 0) return;
        int pb = tlist[3 * blockIdx.x + 1];
        int e2 = tlist[3 * blockIdx.x + 2];
        int hb0 = e2 & 0xFFFF, rcount = e2 >> 16;
        int u = k * 4 + (hb0 >> 6);

        short* Wbuf = (short*)smem;             // 256 rows x 64 bf16 (32 KB)
        short* Xbuf = (short*)(smem + 32768);   // 32 rows x 64 bf16 (4 KB)

        const short* Wg = Wp + (size_t)u * 6 * 16384;
        const short* Xg = Xp + (size_t)pb * 12288;

        f32x4 acc[2][4];
        #pragma unroll
        for (int m = 0; m < 2; m++)
            #pragma unroll
            for (int g = 0; g < 4; g++)
                acc[m][g] = (f32x4){0.f, 0.f, 0.f, 0.f};

        for (int st = 0; st < 6; st++) {
            __syncthreads();
            #pragma unroll
            for (int j = 0; j < 8; j++)
                gl_lds16(Wg + st * 16384 + (w * 64 + j * 8) * 64 + l * 8,
                         smem + (w * 64 + j * 8) * 128);
            gl_lds16(Xg + st * 2048 + w * 512 + l * 8, smem + 32768 + w * 1024);
            __syncthreads();
            #pragma unroll
            for (int ks = 0; ks < 2; ks++) {
                int p = (ks * 4 + quad) ^ (l15 & 7);
                bf16x8 af[2], bfr[4];
                #pragma unroll
                for (int m = 0; m < 2; m++)
                    af[m] = *(bf16x8*)((char*)Xbuf + (m * 16 + l15) * 128 + p * 16);
                #pragma unroll
                for (int g = 0; g < 4; g++)
                    bfr[g] = *(bf16x8*)((char*)Wbuf + (g * 64 + w * 16 + l15) * 128 + p * 16);
                #pragma unroll
                for (int m = 0; m < 2; m++)
                    #pragma unroll
                    for (int g = 0; g < 4; g++)
                        acc[m][g] = __builtin_amdgcn_mfma_f32_16x16x32_bf16(af[m], bfr[g], acc[m][g], 0, 0, 0);
            }
        }

        int h = hb0 + w * 16 + l15;
        float bs[4];
        #pragma unroll
        for (int g = 0; g < 4; g++)
            bs[g] = bsum[(size_t)k * G4H + g * Hdim + h];

        #pragma unroll
        for (int m = 0; m < 2; m++) {
            #pragma unroll
            for (int reg = 0; reg < 4; reg++) {
                int r = m * 16 + quad * 4 + reg;
                if (r < rcount) {
                    int row = pperm[pb * 32 + r];
                    float iv = acc[m][0][reg] + bs[0];
                    float fv = acc[m][1][reg] + bs[1];
                    float gv = acc[m][2][reg] + bs[2];
                    float ov = acc[m][3][reg] + bs[3];
                    float cp = c_prev[(size_t)row * Hdim + h];
                    float cn = sigmoidf_(fv) * cp + sigmoidf_(iv) * tanhf(gv);
                    float hn = sigmoidf_(ov) * tanhf(cn);
                    out[(size_t)row * OUTS + 1 + h] = hn;
                    out[(size_t)row * OUTS + 1 + Hdim + h] = cn;
                }
            }
        }
    } else {
        // ============ loss tile: 32 rows x 80 logits, K=256 ============
        int slot = blockIdx.x - MAXG;
        int cm = tlist2[3 * slot];
        if (cm < 0) return;
        int pb2 = tlist2[3 * slot + 1];
        int rcount = tlist2[3 * slot + 2];

        short* Wlbuf = (short*)smem;              // 80 x 64 bf16 (10240 B)
        short* Vbuf  = (short*)(smem + 10240);    // 32 x 64 bf16 (4096 B)
        float* Lg    = (float*)(smem + 14336);    // 32 x 84 fp32 (10752 B)

        const short* Wg = Wlp + (size_t)cm * 20480;
        const short* Vg = Vp + (size_t)pb2 * 8192;

        f32x4 a0[2], a1[2];
        #pragma unroll
        for (int m = 0; m < 2; m++) { a0[m] = (f32x4){0.f,0.f,0.f,0.f}; a1[m] = (f32x4){0.f,0.f,0.f,0.f}; }

        for (int st = 0; st < 4; st++) {
            __syncthreads();
            for (int n = w; n < 10; n += 4)
                gl_lds16(Wg + st * 5120 + n * 512 + l * 8, smem + n * 1024);
            gl_lds16(Vg + st * 2048 + w * 512 + l * 8, smem + 10240 + w * 1024);
            __syncthreads();
            #pragma unroll
            for (int ks = 0; ks < 2; ks++) {
                int p = (ks * 4 + quad) ^ (l15 & 7);
                bf16x8 af[2];
                af[0] = *(bf16x8*)((char*)Vbuf + l15 * 128 + p * 16);
                af[1] = *(bf16x8*)((char*)Vbuf + (16 + l15) * 128 + p * 16);
                bf16x8 b0 = *(bf16x8*)((char*)Wlbuf + (w * 16 + l15) * 128 + p * 16);
                a0[0] = __builtin_amdgcn_mfma_f32_16x16x32_bf16(af[0], b0, a0[0], 0, 0, 0);
                a0[1] = __builtin_amdgcn_mfma_f32_16x16x32_bf16(af[1], b0, a0[1], 0, 0, 0);
                if (w == 3) {
                    bf16x8 b1 = *(bf16x8*)((char*)Wlbuf + (64 + l15) * 128 + p * 16);
                    a1[0] = __builtin_amdgcn_mfma_f32_16x16x32_bf16(af[0], b1, a1[0], 0, 0, 0);
                    a1[1] = __builtin_amdgcn_mfma_f32_16x16x32_bf16(af[1], b1, a1[1], 0, 0, 0);
                }
            }
        }
        __syncthreads();   // staging done; now reuse smem region for Lg writes
        {
            int col = w * 16 + l15;
            float bb = bl2[cm * 80 + col];
            #pragma unroll
            for (int m = 0; m < 2; m++)
                #pragma unroll
                for (int reg = 0; reg < 4; reg++)
                    Lg[(m * 16 + quad * 4 + reg) * 84 + col] = a0[m][reg] + bb;
            if (w == 3) {
                int col1 = 64 + l15;
                float bb1 = bl2[cm * 80 + col1];
                #pragma unroll
                for (int m = 0; m < 2; m++)
                    #pragma unroll
                    for (int reg = 0; reg < 4; reg++)
                        Lg[(m * 16 + quad * 4 + reg) * 84 + col1] = a1[m][reg] + bb1;
            }
        }
        __syncthreads();
        // per-row softmax-CE: wave w handles rows w*8 .. w*8+7
        for (int rr = 0; rr < 8; rr++) {
            int r = w * 8 + rr;
            if (r >= rcount) break;
            int orig = pperm2[pb2 * 32 + r];
            float lg = Lg[r * 84 + l];
            float mx = lg;
            for (int s = 32; s >= 1; s >>= 1) mx = fmaxf(mx, __shfl_xor(mx, s));
            float sm = expf(lg - mx);
            for (int s = 32; s >= 1; s >>= 1) sm += __shfl_xor(sm, s);
            float lt = __shfl(lg, true_idx[orig]);
            float loss = mx + logf(sm) - lt;
            if (l == 0) {
                float l0 = Lg[r * 84 + 64], l1 = Lg[r * 84 + 65];
                float me = fmaxf(l0, l1);
                loss += me + logf(expf(l0 - me) + expf(l1 - me)) - ((ec_idx[orig] == 0) ? l0 : l1);
                float rl[5] = { Lg[r * 84 + 66], Lg[r * 84 + 67], Lg[r * 84 + 68], Lg[r * 84 + 69], Lg[r * 84 + 70] };
                float mr = rl[0];
                #pragma unroll
                for (int i = 1; i < 5; i++) mr = fmaxf(mr, rl[i]);
                float sr = 0.f;
                #pragma unroll
                for (int i = 0; i < 5; i++) sr += expf(rl[i] - mr);
                loss += mr + logf(sr) - rl[rel_idx[orig]];
                out[(size_t)orig * OUTS] = loss;
            }
        }
    }
}

extern "C" void kernel_launch(void* const* d_in, const int* in_sizes, int n_in,
                              void* d_out, int out_size, void* d_ws, size_t ws_size,
                              hipStream_t stream) {
    const float* vec      = (const float*)d_in[0];
    const float* inp      = (const float*)d_in[1];
    const float* h_prev   = (const float*)d_in[2];
    const float* c_prev   = (const float*)d_in[3];
    const float* Wlin     = (const float*)d_in[4];
    const float* blin     = (const float*)d_in[5];
    const float* Wec      = (const float*)d_in[6];
    const float* bec      = (const float*)d_in[7];
    const float* Wrel     = (const float*)d_in[8];
    const float* brel     = (const float*)d_in[9];
    const float* W_ih     = (const float*)d_in[10];
    const float* b_ih     = (const float*)d_in[11];
    const float* W_hh     = (const float*)d_in[12];
    const float* b_hh     = (const float*)d_in[13];
    const int*   category = (const int*)d_in[14];
    const int*   cell_id  = (const int*)d_in[15];
    const int*   true_idx = (const int*)d_in[16];
    const int*   ec_idx   = (const int*)d_in[17];
    const int*   rel_idx  = (const int*)d_in[18];
    float* out = (float*)d_out;

    char* ws = (char*)d_ws;
    int*   pperm  = (int*)(ws);                    // 4736 ints
    int*   pperm2 = (int*)(ws + 18944);            // 5120 ints
    int*   tlist  = (int*)(ws + 39424);            // 3*1280
    int*   tlist2 = (int*)(ws + 54784);            // 3*192
    int*   meta   = (int*)(ws + 57088);            // 16
    short* Wp     = (short*)(ws + 57344);          // 7,864,320 bf16
    short* Xp     = (short*)(ws + 15785984);       // 1,818,624 bf16
    short* Vp     = (short*)(ws + 19423232);       // 1,310,720 bf16
    short* Wlp    = (short*)(ws + 22044672);       // 655,360 bf16
    float* bsum   = (float*)(ws + 23355392);       // 20,480 fp32
    float* bl2    = (float*)(ws + 23437312);       // 2,560 fp32

    k_bucket<<<1, 1024, 0, stream>>>(cell_id, category, pperm, pperm2, tlist, tlist2, meta);

    k_pack<<<PACK_T / 256, 256, 0, stream>>>(
        vec, inp, h_prev, Wlin, blin, Wec, bec, Wrel, brel,
        W_ih, b_ih, W_hh, b_hh, pperm, pperm2, meta,
        Wp, Xp, Vp, Wlp, bsum, bl2);

    k_main<<<MAXG + MAXT2, 256, 0, stream>>>(
        c_prev, Wp, Xp, Vp, Wlp, bsum, bl2,
        pperm, pperm2, tlist, tlist2, true_idx, ec_idx, rel_idx, out);
}